// Round 2
// baseline (270.545 us; speedup 1.0000x reference)
//
#include <hip/hip_runtime.h>
#include <math.h>

// x: (B=64, C=3, H=512, W=512) fp32.  out: (64, 18) fp32.
// Per 8x8 block: |FFT2| at bands (0,1),(1,0),(1,1),(2,2),(3,3),(4,4); mean over
// the 64x64 block grid.
//
// Column-DFT-first layout: one wave = 8 rows x 256 cols strip (32 blocks).
// Lane i owns 4 adjacent columns -> float4 load at base+16*i is perfectly
// coalesced (1 KB contiguous per wave instruction, each 64B line touched once).
// Horizontal twiddles: c_local = (4*lane+k) & 7; lane parity only flips the
// sign of the v in {1,3} bands (e^{-i*pi} = -1), so all twiddles fold to
// compile-time constants per unrolled k.

#define IMG_W 512
#define IMG_PIX (512 * 512)

__global__ __launch_bounds__(256) void dct_band_kernel(const float* __restrict__ x,
                                                       float* __restrict__ out) {
    const int t    = threadIdx.x;
    const int lane = t & 63;
    const int wave = t >> 6;
    const int w    = blockIdx.x * 4 + wave;  // global wave id 0..24575
    const int img  = w >> 7;                 // 0..191 (b*3+c)
    const int bR   = (w >> 1) & 63;          // block-row 0..63
    const int half = w & 1;                  // 256-col half

    const float* p = x + (size_t)img * IMG_PIX
                       + (size_t)(bR * 8) * IMG_W + half * 256 + lane * 4;

    // 8 fully-coalesced float4 loads (8 KB per wave, contiguous per instr)
    float4 row[8];
#pragma unroll
    for (int r = 0; r < 8; ++r)
        row[r] = *(const float4*)(p + (size_t)r * IMG_W);

    const float C1 = 0.70710678118654752440f;
    // e^{-2*pi*i*k/8} = ct[k] - i*st[k]
    const float ct[8] = {1.f,  C1, 0.f, -C1, -1.f, -C1, 0.f,  C1};
    const float st[8] = {0.f,  C1, 1.f,  C1,  0.f, -C1, -1.f, -C1};

    float F01r = 0.f, F01i = 0.f;  // (u=0,v=1)
    float F10r = 0.f, F10i = 0.f;  // (u=1,v=0)
    float F11r = 0.f, F11i = 0.f;  // (u=1,v=1)
    float F22r = 0.f, F22i = 0.f;  // (u=2,v=2)
    float F33r = 0.f, F33i = 0.f;  // (u=3,v=3)
    float F44  = 0.f;              // (u=4,v=4) real

#pragma unroll
    for (int k = 0; k < 4; ++k) {
        const float x0 = (&row[0].x)[k];
        const float x1 = (&row[1].x)[k];
        const float x2 = (&row[2].x)[k];
        const float x3 = (&row[3].x)[k];
        const float x4 = (&row[4].x)[k];
        const float x5 = (&row[5].x)[k];
        const float x6 = (&row[6].x)[k];
        const float x7 = (&row[7].x)[k];

        // column DFT, bins u=0..4 : H[u] = sum_r x_r e^{-2*pi*i*u*r/8}
        const float h0  = x0 + x1 + x2 + x3 + x4 + x5 + x6 + x7;
        const float h1r = x0 - x4 + C1 * (x1 - x3 - x5 + x7);
        const float h1i = -(C1 * (x1 + x3 - x5 - x7) + x2 - x6);
        const float h2r = x0 - x2 + x4 - x6;
        const float h2i = -(x1 - x3 + x5 - x7);
        const float h3r = x0 - x4 + C1 * (-x1 + x3 + x5 - x7);
        const float h3i = -(C1 * (x1 + x3 - x5 - x7) - x2 + x6);
        const float h4  = x0 - x1 + x2 - x3 + x4 - x5 + x6 - x7;

        // horizontal twiddles at local col k (lane parity handled after loop)
        const float c1 = ct[k],           s1 = st[k];            // v=1
        const float c2 = ct[(2 * k) & 7], s2 = st[(2 * k) & 7];  // v=2
        const float c3 = ct[(3 * k) & 7], s3 = st[(3 * k) & 7];  // v=3
        const float w4 = (k & 1) ? -1.f : 1.f;                   // v=4

        // (hr + i*hi)*(c - i*s) = (hr*c + hi*s) + i*(hi*c - hr*s)
        F01r += h0 * c1;               F01i -= h0 * s1;
        F10r += h1r;                   F10i += h1i;
        F11r += h1r * c1 + h1i * s1;   F11i += h1i * c1 - h1r * s1;
        F22r += h2r * c2 + h2i * s2;   F22i += h2i * c2 - h2r * s2;
        F33r += h3r * c3 + h3i * s3;   F33i += h3i * c3 - h3r * s3;
        F44  += h4 * w4;
    }

    // lane parity sign for v in {1,3} bands: cols of odd lanes are c = k+4,
    // and e^{-2*pi*i*v*(k+4)/8} = -e^{-2*pi*i*v*k/8} for odd v.
    const float sgn = (lane & 1) ? -1.f : 1.f;
    F01r *= sgn; F01i *= sgn;
    F11r *= sgn; F11i *= sgn;
    F33r *= sgn; F33i *= sgn;

    // combine the two threads (lane pair) that share one 8-wide block
    F01r += __shfl_xor(F01r, 1); F01i += __shfl_xor(F01i, 1);
    F10r += __shfl_xor(F10r, 1); F10i += __shfl_xor(F10i, 1);
    F11r += __shfl_xor(F11r, 1); F11i += __shfl_xor(F11i, 1);
    F22r += __shfl_xor(F22r, 1); F22i += __shfl_xor(F22i, 1);
    F33r += __shfl_xor(F33r, 1); F33i += __shfl_xor(F33i, 1);
    F44  += __shfl_xor(F44, 1);

    float m[6];
    m[0] = sqrtf(F01r * F01r + F01i * F01i);
    m[1] = sqrtf(F10r * F10r + F10i * F10i);
    m[2] = sqrtf(F11r * F11r + F11i * F11i);
    m[3] = sqrtf(F22r * F22r + F22i * F22i);
    m[4] = sqrtf(F33r * F33r + F33i * F33i);
    m[5] = fabsf(F44);
    // every block's magnitude now lives in BOTH lanes of its pair -> the wave
    // sum below counts each block twice; compensate with 1/8192 at the end.

#pragma unroll
    for (int off = 32; off > 0; off >>= 1) {
#pragma unroll
        for (int k = 0; k < 6; ++k) m[k] += __shfl_down(m[k], off);
    }

    __shared__ float red[4][6];
    if (lane == 0) {
#pragma unroll
        for (int k = 0; k < 6; ++k) red[wave][k] = m[k];
    }
    __syncthreads();

    if (t < 6) {
        const float s = red[0][t] + red[1][t] + red[2][t] + red[3][t];
        atomicAdd(&out[img * 6 + t], s * (1.0f / 8192.0f));
    }
}

extern "C" void kernel_launch(void* const* d_in, const int* in_sizes, int n_in,
                              void* d_out, int out_size, void* d_ws, size_t ws_size,
                              hipStream_t stream) {
    const float* x = (const float*)d_in[0];
    float* out = (float*)d_out;

    // d_out is poisoned 0xAA before every call — zero it for the atomics.
    hipMemsetAsync(d_out, 0, (size_t)out_size * sizeof(float), stream);

    // 24576 waves total: 192 images x 64 block-rows x 2 halves; 4 waves / WG
    dim3 grid(6144);
    dim3 block(256);
    dct_band_kernel<<<grid, block, 0, stream>>>(x, out);
}